// Round 9
// baseline (266.870 us; speedup 1.0000x reference)
//
#include <hip/hip_runtime.h>

#define HW 4608      // 48*96
#define NB 16
#define CC 256
#define SS 64
#define EPS 1e-5f
#define NSPLIT 24    // k_graph split-K (atomic accumulate)

typedef __attribute__((ext_vector_type(8))) short short8;
typedef __attribute__((ext_vector_type(4))) float f32x4;

__device__ __forceinline__ ushort f2bf(float f) {
    uint u = __float_as_uint(f);
    return (ushort)((u + 0x7FFFu + ((u >> 16) & 1u)) >> 16);
}
__device__ __forceinline__ float bf2f(ushort h) {
    return __uint_as_float(((uint)h) << 16);
}

// ---------------- K0: pack W fragment-ready: Wf[cs][kq][r][j] bf16, c = cs*32+kq*8+j ----------
__global__ __launch_bounds__(256) void k_wf(const float* __restrict__ Ws,
                                            const float* __restrict__ Wp,
                                            ushort* __restrict__ Wf) {
    int idx = blockIdx.x * 256 + threadIdx.x;      // 0..32767
    int j = idx & 7, r = (idx >> 3) & 127, kq = (idx >> 10) & 3, cs = idx >> 12;
    int c = cs * 32 + kq * 8 + j;
    float v = (r < 64) ? Ws[r * CC + c] : Wp[(r - 64) * CC + c];
    Wf[idx] = f2bf(v);
}

// ---------------- K1: MFMA proj v6: v2 + LDS double-buffer + RAW barrier (no vmcnt drain) ----
// grid (72, NB), 256 thr (4 waves). One raw s_barrier per cs (lgkmcnt(0) only), so the
// cs+1 x/Wf prefetch loads stay outstanding across the barrier and drain only at their
// consumption (f2bf of next iter) -> true cross-iteration latency hiding.
// WAR safety: at write of buf[b]@cs, all waves passed barrier@cs-1 => finished reads of
// buf[b]@cs-2 (reads of cs-2 precede barrier@cs-1 in program order).
__global__ __launch_bounds__(256) void k_proj(const float* __restrict__ x,
                                              const ushort* __restrict__ Wf,
                                              const float* __restrict__ bs,
                                              const float* __restrict__ bp,
                                              const float* __restrict__ edge,
                                              ushort* __restrict__ xsb,
                                              ushort* __restrict__ Eb,
                                              float* __restrict__ rsum) {
    __shared__ __align__(16) ushort Bl[2][4 * 64 * 8];   // [buf][kq][col][8] = 8 KB
    int n = blockIdx.y, k0 = blockIdx.x * 64;
    int tid = threadIdx.x, lane = tid & 63, w = tid >> 6;
    int q = lane >> 4, li = lane & 15;
    f32x4 acc[2][4] = {};
    const float* xb = x + (size_t)n * CC * HW + k0 + lane;  // staging: col=lane, ch-group kq=w
    float pf[8];
    uint4 afn[2];
    // prologue: issue loads for cs=0 (x staging values + A-fragments)
#pragma unroll
    for (int j = 0; j < 8; j++) pf[j] = xb[(size_t)(w * 8 + j) * HW];
#pragma unroll
    for (int mt = 0; mt < 2; mt++)
        afn[mt] = *(const uint4*)&Wf[((0 * 4 + q) * 128 + w * 32 + mt * 16 + li) * 8];
#pragma unroll 2
    for (int cs = 0; cs < 8; cs++) {
        int b = cs & 1;
        // consume prefetched regs (vmcnt wait lands here, after a full iteration in flight)
        union { ushort u[8]; uint4 v; } tmp;
#pragma unroll
        for (int j = 0; j < 8; j++) tmp.u[j] = f2bf(pf[j]);
        short8 af[2];
        af[0] = *(short8*)&afn[0];
        af[1] = *(short8*)&afn[1];
        *(uint4*)&Bl[b][(w * 64 + lane) * 8] = tmp.v;
        asm volatile("s_waitcnt lgkmcnt(0)" ::: "memory");   // LDS visibility only
        __builtin_amdgcn_s_barrier();                        // raw: no vmcnt drain
        // issue next-iter global loads: they stay in flight across next barrier
        if (cs < 7) {
#pragma unroll
            for (int j = 0; j < 8; j++)
                pf[j] = xb[(size_t)((cs + 1) * 32 + w * 8 + j) * HW];
#pragma unroll
            for (int mt = 0; mt < 2; mt++)
                afn[mt] = *(const uint4*)&Wf[(((cs + 1) * 4 + q) * 128 + w * 32 + mt * 16 + li) * 8];
        }
        short8 bfr[4];
#pragma unroll
        for (int nt = 0; nt < 4; nt++) {
            uint4 t = *(const uint4*)&Bl[b][(q * 64 + nt * 16 + li) * 8];
            bfr[nt] = *(short8*)&t;
        }
#pragma unroll
        for (int mt = 0; mt < 2; mt++)
#pragma unroll
            for (int nt = 0; nt < 4; nt++)
                acc[mt][nt] = __builtin_amdgcn_mfma_f32_16x16x32_bf16(af[mt], bfr[nt], acc[mt][nt], 0, 0, 0);
        // no trailing barrier: next write goes to the other buffer
    }
    // epilogue: rows w*32 + mt*16 + q*4 + rr ; cols k0 + nt*16 + li
    if (w < 2) {
#pragma unroll
        for (int mt = 0; mt < 2; mt++) {
#pragma unroll
            for (int rr = 0; rr < 4; rr++) {
                int s = w * 32 + mt * 16 + q * 4 + rr;
                float bv = bs[s];
#pragma unroll
                for (int nt = 0; nt < 4; nt++) {
                    int col = k0 + nt * 16 + li;
                    xsb[((size_t)n * SS + s) * HW + col] = f2bf(acc[mt][nt][rr] + bv);
                }
            }
        }
    } else {
        float ga[4];
#pragma unroll
        for (int nt = 0; nt < 4; nt++) {
            int col = k0 + nt * 16 + li;
            float e0 = edge[((size_t)n * 2 + 0) * HW + col];
            float e1 = edge[((size_t)n * 2 + 1) * HW + col];
            ga[nt] = 1.f + 1.f / (1.f + __expf(e0 - e1));
        }
        float rp[2][4];
#pragma unroll
        for (int mt = 0; mt < 2; mt++) {
#pragma unroll
            for (int rr = 0; rr < 4; rr++) {
                int s = (w - 2) * 32 + mt * 16 + q * 4 + rr;
                float bv = bp[s];
                float sum = 0.f;
#pragma unroll
                for (int nt = 0; nt < 4; nt++) {
                    int col = k0 + nt * 16 + li;
                    float e = __expf((acc[mt][nt][rr] + bv) * ga[nt]);
                    sum += e;
                    Eb[((size_t)n * SS + s) * HW + col] = f2bf(e);
                }
                rp[mt][rr] = sum;
            }
        }
#pragma unroll
        for (int b = 1; b < 16; b <<= 1)
#pragma unroll
            for (int mt = 0; mt < 2; mt++)
#pragma unroll
                for (int rr = 0; rr < 4; rr++)
                    rp[mt][rr] += __shfl_xor(rp[mt][rr], b, 64);
        if (li == 0) {
#pragma unroll
            for (int mt = 0; mt < 2; mt++)
#pragma unroll
                for (int rr = 0; rr < 4; rr++)
                    atomicAdd(&rsum[n * SS + (w - 2) * 32 + mt * 16 + q * 4 + rr], rp[mt][rr]);
        }
    }
}

// ---------------- K2: MFMA graph: U = xs@E^T, P = E@E^T, split-K -> atomic accumulate -------
__global__ __launch_bounds__(256) void k_graph(const ushort* __restrict__ xsb,
                                               const ushort* __restrict__ Eb,
                                               float* __restrict__ U,
                                               float* __restrict__ P) {
    int n = blockIdx.y, sp = blockIdx.x;
    int kbase = sp * (HW / NSPLIT);
    int tid = threadIdx.x, lane = tid & 63, w = tid >> 6;
    int q = lane >> 4, li = lane & 15;
    bool isP = w >= 2;
    int half = w & 1;
    const ushort* Arow = isP ? Eb : xsb;
    f32x4 acc[2][4] = {};
    for (int ks = 0; ks < (HW / NSPLIT) / 32; ks++) {
        int kb = kbase + ks * 32 + q * 8;
        short8 af[2], bfr[4];
#pragma unroll
        for (int mt = 0; mt < 2; mt++) {
            int s = half * 32 + mt * 16 + li;
            uint4 t = *(const uint4*)&Arow[((size_t)n * SS + s) * HW + kb];
            af[mt] = *(short8*)&t;
        }
#pragma unroll
        for (int nt = 0; nt < 4; nt++) {
            int tt = nt * 16 + li;
            uint4 t = *(const uint4*)&Eb[((size_t)n * SS + tt) * HW + kb];
            bfr[nt] = *(short8*)&t;
        }
#pragma unroll
        for (int mt = 0; mt < 2; mt++)
#pragma unroll
            for (int nt = 0; nt < 4; nt++)
                acc[mt][nt] = __builtin_amdgcn_mfma_f32_16x16x32_bf16(af[mt], bfr[nt], acc[mt][nt], 0, 0, 0);
    }
    float* dst = (isP ? P : U) + (size_t)n * 4096;
#pragma unroll
    for (int mt = 0; mt < 2; mt++)
#pragma unroll
        for (int nt = 0; nt < 4; nt++)
#pragma unroll
            for (int rr = 0; rr < 4; rr++) {
                int row = half * 32 + mt * 16 + q * 4 + rr;
                int col = nt * 16 + li;
                atomicAdd(&dst[row * 64 + col], acc[mt][nt][rr]);
            }
}

// ---------------- K3: GCN + fold We: M' fp32 [c][t] AND bf16 fragment-ready Mf --------------
__global__ __launch_bounds__(256) void k_gcn(const float* __restrict__ U,
                                             const float* __restrict__ rsum,
                                             const float* __restrict__ W1,
                                             const float* __restrict__ W2,
                                             const float* __restrict__ We,
                                             float* __restrict__ M,
                                             ushort* __restrict__ Mf) {
    __shared__ __align__(16) float A[64 * 68];
    __shared__ __align__(16) float B[64 * 68];
    __shared__ __align__(16) float Cb[64 * 68];
    __shared__ float rs[64];
    int n = blockIdx.x;
    int cc = blockIdx.y;
    int tid = threadIdx.x;
    int t0 = tid >> 4, t1 = tid & 15;
    if (tid < 64) rs[tid] = 1.0f / rsum[n * SS + tid];
    __syncthreads();
#pragma unroll
    for (int i = 0; i < 16; i++) {
        int idx = tid + i * 256;
        int r = idx >> 6, cth = idx & 63;
        A[cth * 68 + r] = U[n * 4096 + idx] * rs[cth];
        B[cth * 68 + r] = W1[idx];
    }
    __syncthreads();
    {
        float acc[4][4] = {};
        for (int j = 0; j < 64; j++) {
            float4 a4 = *(const float4*)&A[j * 68 + t0 * 4];
            float4 b4 = *(const float4*)&B[j * 68 + t1 * 4];
            float a[4] = {a4.x, a4.y, a4.z, a4.w};
            float b[4] = {b4.x, b4.y, b4.z, b4.w};
#pragma unroll
            for (int p = 0; p < 4; p++)
#pragma unroll
                for (int qq = 0; qq < 4; qq++) acc[p][qq] += a[p] * b[qq];
        }
#pragma unroll
        for (int p = 0; p < 4; p++)
#pragma unroll
            for (int qq = 0; qq < 4; qq++) {
                acc[p][qq] -= A[(t1 * 4 + qq) * 68 + (t0 * 4 + p)];
                Cb[(t0 * 4 + p) * 68 + t1 * 4 + qq] = acc[p][qq];
            }
    }
    __syncthreads();
#pragma unroll
    for (int i = 0; i < 16; i++) {
        int idx = tid + i * 256;
        int r = idx >> 6, cth = idx & 63;
        B[cth * 68 + r] = W2[idx];
    }
    __syncthreads();
    {
        float acc[4][4] = {};
        for (int j = 0; j < 64; j++) {
            float4 a4 = *(const float4*)&B[j * 68 + t0 * 4];
            float4 b4 = *(const float4*)&Cb[j * 68 + t1 * 4];
            float a[4] = {a4.x, a4.y, a4.z, a4.w};
            float b[4] = {b4.x, b4.y, b4.z, b4.w};
#pragma unroll
            for (int p = 0; p < 4; p++)
#pragma unroll
                for (int qq = 0; qq < 4; qq++) acc[p][qq] += a[p] * b[qq];
        }
        __syncthreads();
#pragma unroll
        for (int p = 0; p < 4; p++)
#pragma unroll
            for (int qq = 0; qq < 4; qq++)
                A[(t0 * 4 + p) * 68 + t1 * 4 + qq] = fmaxf(acc[p][qq], 0.f);
    }
    __syncthreads();
#pragma unroll
    for (int i = 0; i < 16; i++) {
        int idx = tid + i * 256;
        int c = idx >> 6, j = idx & 63;
        B[j * 68 + c] = We[(cc * 64 + c) * 64 + j];
    }
    __syncthreads();
    {
        float acc[4][4] = {};
        for (int j = 0; j < 64; j++) {
            float4 a4 = *(const float4*)&B[j * 68 + t0 * 4];
            float4 b4 = *(const float4*)&A[j * 68 + t1 * 4];
            float a[4] = {a4.x, a4.y, a4.z, a4.w};
            float b[4] = {b4.x, b4.y, b4.z, b4.w};
#pragma unroll
            for (int p = 0; p < 4; p++)
#pragma unroll
                for (int qq = 0; qq < 4; qq++) acc[p][qq] += a[p] * b[qq];
        }
#pragma unroll
        for (int p = 0; p < 4; p++) {
            int c = cc * 64 + t0 * 4 + p;
            float v[4];
#pragma unroll
            for (int qq = 0; qq < 4; qq++) v[qq] = acc[p][qq] * rs[t1 * 4 + qq];
            float4 st = {v[0], v[1], v[2], v[3]};
            *(float4*)&M[((size_t)n * CC + c) * 64 + t1 * 4] = st;
#pragma unroll
            for (int qq = 0; qq < 4; qq++) {
                int t = t1 * 4 + qq;
                Mf[(size_t)n * 16384 + ((t >> 3) * 256 + c) * 8 + (t & 7)] = f2bf(v[qq]);
            }
        }
    }
}

// ---------------- K4: BN stats -> scale/bias (all-n LDS preload, 2-barrier body) ----------------
__global__ __launch_bounds__(256) void k_stats(const float* __restrict__ M,
                                               const float* __restrict__ P,
                                               const float* __restrict__ rsum,
                                               const float* __restrict__ gamma,
                                               const float* __restrict__ beta,
                                               float* __restrict__ sc,
                                               float* __restrict__ bi) {
    __shared__ float ms[NB][64];     // 4 KB: M rows for this channel, all n
    __shared__ float red[256];
    int c = blockIdx.x;
    int tid = threadIdx.x;
    for (int i = tid; i < NB * 64; i += 256) {
        int n = i >> 6, s = i & 63;
        ms[n][s] = M[((size_t)n * CC + c) * 64 + s];
    }
    __syncthreads();
    float qa = 0.f;
    for (int n = 0; n < NB; n++) {
        const float* Pn = P + n * 4096;
#pragma unroll
        for (int p = 0; p < 16; p++) {
            int e = p * 256 + tid;
            qa += ms[n][e >> 6] * ms[n][e & 63] * Pn[e];
        }
    }
    float sa = 0.f;
    for (int i = tid; i < NB * 64; i += 256) {
        int n = i >> 6, s = i & 63;
        sa += ms[n][s] * rsum[n * SS + s];
    }
    red[tid] = qa;
    __syncthreads();
    for (int off = 128; off > 0; off >>= 1) {
        if (tid < off) red[tid] += red[tid + off];
        __syncthreads();
    }
    float qtot = red[0];
    __syncthreads();
    red[tid] = sa;
    __syncthreads();
    for (int off = 128; off > 0; off >>= 1) {
        if (tid < off) red[tid] += red[tid + off];
        __syncthreads();
    }
    if (tid == 0) {
        float stot = red[0];
        const float invM = 1.0f / ((float)NB * (float)HW);
        float mean = stot * invM;
        float var = qtot * invM - mean * mean;
        float s = gamma[c] * rsqrtf(var + EPS);
        sc[c] = s;
        bi[c] = beta[c] - s * mean;
    }
}

// ---------------- K5: MFMA out v2: 128c x 128k tile, float4 x/out via LDS transpose ---------
// grid (72, NB): bx = kt*2 + ct. 4 waves, wave w owns c-rows [c0+w*32, +32) x all 128 k.
// Epilogue: 2 chunks of 64 c-rows through LDS (aliases staging buf), float4 global I/O
// (512 B row segments, 16 B/lane) instead of 64 scalar loads + 64 scalar stores.
__global__ __launch_bounds__(256) void k_out(const float* __restrict__ x,
                                             const ushort* __restrict__ Mf,
                                             const ushort* __restrict__ Eb,
                                             const float* __restrict__ sc,
                                             const float* __restrict__ bi,
                                             float* __restrict__ out) {
    __shared__ __align__(16) char shb[64 * 132 * 4];   // 33792 B
    ushort* Bl = (ushort*)shb;     // staging frag [kq 0..7][col 0..127][8] = 16 KB
    float* E2 = (float*)shb;       // epilogue chunk [64][132]
    int n = blockIdx.y;
    int kt = blockIdx.x >> 1, ct = blockIdx.x & 1;
    int k0 = kt * 128, c0 = ct * 128;
    int tid = threadIdx.x, lane = tid & 63, w = tid >> 6;
    int q = lane >> 4, li = lane & 15;
    {
        int nl = tid & 127, pr = tid >> 7;
#pragma unroll
        for (int kk = 0; kk < 4; kk++) {
            int kq = pr * 4 + kk;
            union { ushort u[8]; uint4 v; } tmp;
#pragma unroll
            for (int j = 0; j < 8; j++)
                tmp.u[j] = Eb[((size_t)n * SS + kq * 8 + j) * HW + k0 + nl];
            *(uint4*)&Bl[(kq * 128 + nl) * 8] = tmp.v;
        }
    }
    __syncthreads();
    f32x4 acc[2][8] = {};
#pragma unroll
    for (int ks = 0; ks < 2; ks++) {
        short8 af[2], bfr[8];
#pragma unroll
        for (int mt = 0; mt < 2; mt++) {
            int c = c0 + w * 32 + mt * 16 + li;
            uint4 t = *(const uint4*)&Mf[(size_t)n * 16384 + ((ks * 4 + q) * 256 + c) * 8];
            af[mt] = *(short8*)&t;
        }
#pragma unroll
        for (int nt = 0; nt < 8; nt++) {
            int nl = nt * 16 + li;
            uint4 t = *(const uint4*)&Bl[((ks * 4 + q) * 128 + nl) * 8];
            bfr[nt] = *(short8*)&t;
        }
#pragma unroll
        for (int mt = 0; mt < 2; mt++)
#pragma unroll
            for (int nt = 0; nt < 8; nt++)
                acc[mt][nt] = __builtin_amdgcn_mfma_f32_16x16x32_bf16(af[mt], bfr[nt], acc[mt][nt], 0, 0, 0);
    }
#pragma unroll 1
    for (int mtc = 0; mtc < 2; mtc++) {
        __syncthreads();     // protect E2 (aliases Bl on first pass / prev chunk after)
#pragma unroll
        for (int nt = 0; nt < 8; nt++)
#pragma unroll
            for (int rr = 0; rr < 4; rr++)
                E2[(w * 16 + q * 4 + rr) * 132 + nt * 16 + li] = acc[mtc][nt][rr];
        __syncthreads();
#pragma unroll
        for (int i = 0; i < 8; i++) {
            int r = (tid >> 5) + i * 8;            // 0..63
            int c4 = tid & 31;
            int c = c0 + (r >> 4) * 32 + mtc * 16 + (r & 15);
            float s_ = sc[c], bv = bi[c];
            float4 av = *(const float4*)&E2[r * 132 + c4 * 4];
            size_t base = ((size_t)n * CC + c) * HW + k0 + c4 * 4;
            float4 xv = *(const float4*)&x[base];
            float4 o;
            o.x = xv.x + s_ * av.x + bv;
            o.y = xv.y + s_ * av.y + bv;
            o.z = xv.z + s_ * av.z + bv;
            o.w = xv.w + s_ * av.w + bv;
            *(float4*)&out[base] = o;
        }
    }
}

extern "C" void kernel_launch(void* const* d_in, const int* in_sizes, int n_in,
                              void* d_out, int out_size, void* d_ws, size_t ws_size,
                              hipStream_t stream) {
    const float* x = (const float*)d_in[0];
    const float* edge = (const float*)d_in[1];
    const float* Ws = (const float*)d_in[2];
    const float* bs = (const float*)d_in[3];
    const float* Wp = (const float*)d_in[4];
    const float* bp = (const float*)d_in[5];
    const float* W1 = (const float*)d_in[6];
    const float* W2 = (const float*)d_in[7];
    const float* We = (const float*)d_in[8];
    const float* gamma = (const float*)d_in[9];
    const float* beta = (const float*)d_in[10];
    float* out = (float*)d_out;

    char* base = (char*)d_ws;
    ushort* Wf  = (ushort*)base;                    base += 65536;           // 64 KB
    ushort* xsb = (ushort*)base;                    base += 9437184;         // 9 MB
    ushort* Eb  = (ushort*)base;                    base += 9437184;
    float*  rsum= (float*)base;                     base += 4096;            // zeroed region start
    float*  U   = (float*)base;                     base += 262144;
    float*  P   = (float*)base;                     base += 262144;
    float*  M   = (float*)base;                     base += 1048576;
    ushort* Mf  = (ushort*)base;                    base += 524288;
    float*  sc  = (float*)base;                     base += 1024;
    float*  bi  = (float*)base;                     base += 1024;

    // zero rsum + U + P in one contiguous memset (4 KB + 256 KB + 256 KB)
    hipMemsetAsync(rsum, 0, 4096 + 262144 + 262144, stream);
    k_wf<<<128, 256, 0, stream>>>(Ws, Wp, Wf);
    k_proj<<<dim3(72, NB), 256, 0, stream>>>(x, Wf, bs, bp, edge, xsb, Eb, rsum);
    k_graph<<<dim3(NSPLIT, NB), 256, 0, stream>>>(xsb, Eb, U, P);
    k_gcn<<<dim3(NB, 4), 256, 0, stream>>>(U, rsum, W1, W2, We, M, Mf);
    k_stats<<<256, 256, 0, stream>>>(M, P, rsum, gamma, beta, sc, bi);
    k_out<<<dim3(72, NB), 256, 0, stream>>>(x, Mf, Eb, sc, bi, out);
}

// Round 10
// 225.000 us; speedup vs baseline: 1.1861x; 1.1861x over previous
//
#include <hip/hip_runtime.h>

#define HW 4608      // 48*96
#define NB 16
#define CC 256
#define SS 64
#define EPS 1e-5f
#define NSPLIT 24    // k_graph split-K (atomic accumulate)

typedef __attribute__((ext_vector_type(8))) short short8;
typedef __attribute__((ext_vector_type(4))) float f32x4;

__device__ __forceinline__ ushort f2bf(float f) {
    uint u = __float_as_uint(f);
    return (ushort)((u + 0x7FFFu + ((u >> 16) & 1u)) >> 16);
}
__device__ __forceinline__ float bf2f(ushort h) {
    return __uint_as_float(((uint)h) << 16);
}

// ---------------- K0: pack W fragment-ready: Wf[cs][kq][r][j] bf16, c = cs*32+kq*8+j ----------
__global__ __launch_bounds__(256) void k_wf(const float* __restrict__ Ws,
                                            const float* __restrict__ Wp,
                                            ushort* __restrict__ Wf) {
    int idx = blockIdx.x * 256 + threadIdx.x;      // 0..32767
    int j = idx & 7, r = (idx >> 3) & 127, kq = (idx >> 10) & 3, cs = idx >> 12;
    int c = cs * 32 + kq * 8 + j;
    float v = (r < 64) ? Ws[r * CC + c] : Wp[(r - 64) * CC + c];
    Wf[idx] = f2bf(v);
}

// ---------------- K1: MFMA proj v2 (verified 45.4us): 128r x 64k tile, reg-prefetch ---------
// grid (72, NB), 256 thr (4 waves). Wave w owns rows w*32..w*32+31. K=C=256 in 8 steps.
__global__ __launch_bounds__(256) void k_proj(const float* __restrict__ x,
                                              const ushort* __restrict__ Wf,
                                              const float* __restrict__ bs,
                                              const float* __restrict__ bp,
                                              const float* __restrict__ edge,
                                              ushort* __restrict__ xsb,
                                              ushort* __restrict__ Eb,
                                              float* __restrict__ rsum) {
    __shared__ __align__(16) ushort Bl[4 * 64 * 8];   // [kq][col][8] = 4 KB
    int n = blockIdx.y, k0 = blockIdx.x * 64;
    int tid = threadIdx.x, lane = tid & 63, w = tid >> 6;
    int q = lane >> 4, li = lane & 15;
    f32x4 acc[2][4] = {};
    const float* xb = x + (size_t)n * CC * HW + k0 + lane;  // staging: col=lane, ch-group kq=w
    float pf[8];
    uint4 afn[2];
#pragma unroll
    for (int j = 0; j < 8; j++) pf[j] = xb[(size_t)(w * 8 + j) * HW];
#pragma unroll
    for (int mt = 0; mt < 2; mt++)
        afn[mt] = *(const uint4*)&Wf[((0 * 4 + q) * 128 + w * 32 + mt * 16 + li) * 8];
#pragma unroll 1
    for (int cs = 0; cs < 8; cs++) {
        union { ushort u[8]; uint4 v; } tmp;
#pragma unroll
        for (int j = 0; j < 8; j++) tmp.u[j] = f2bf(pf[j]);
        short8 af[2];
        af[0] = *(short8*)&afn[0];
        af[1] = *(short8*)&afn[1];
        *(uint4*)&Bl[(w * 64 + lane) * 8] = tmp.v;
        __syncthreads();
        if (cs < 7) {
#pragma unroll
            for (int j = 0; j < 8; j++)
                pf[j] = xb[(size_t)((cs + 1) * 32 + w * 8 + j) * HW];
#pragma unroll
            for (int mt = 0; mt < 2; mt++)
                afn[mt] = *(const uint4*)&Wf[(((cs + 1) * 4 + q) * 128 + w * 32 + mt * 16 + li) * 8];
        }
        short8 bfr[4];
#pragma unroll
        for (int nt = 0; nt < 4; nt++) {
            uint4 t = *(const uint4*)&Bl[(q * 64 + nt * 16 + li) * 8];
            bfr[nt] = *(short8*)&t;
        }
#pragma unroll
        for (int mt = 0; mt < 2; mt++)
#pragma unroll
            for (int nt = 0; nt < 4; nt++)
                acc[mt][nt] = __builtin_amdgcn_mfma_f32_16x16x32_bf16(af[mt], bfr[nt], acc[mt][nt], 0, 0, 0);
        __syncthreads();
    }
    // epilogue: rows w*32 + mt*16 + q*4 + rr ; cols k0 + nt*16 + li
    if (w < 2) {
#pragma unroll
        for (int mt = 0; mt < 2; mt++) {
#pragma unroll
            for (int rr = 0; rr < 4; rr++) {
                int s = w * 32 + mt * 16 + q * 4 + rr;
                float bv = bs[s];
#pragma unroll
                for (int nt = 0; nt < 4; nt++) {
                    int col = k0 + nt * 16 + li;
                    xsb[((size_t)n * SS + s) * HW + col] = f2bf(acc[mt][nt][rr] + bv);
                }
            }
        }
    } else {
        float ga[4];
#pragma unroll
        for (int nt = 0; nt < 4; nt++) {
            int col = k0 + nt * 16 + li;
            float e0 = edge[((size_t)n * 2 + 0) * HW + col];
            float e1 = edge[((size_t)n * 2 + 1) * HW + col];
            ga[nt] = 1.f + 1.f / (1.f + __expf(e0 - e1));
        }
        float rp[2][4];
#pragma unroll
        for (int mt = 0; mt < 2; mt++) {
#pragma unroll
            for (int rr = 0; rr < 4; rr++) {
                int s = (w - 2) * 32 + mt * 16 + q * 4 + rr;
                float bv = bp[s];
                float sum = 0.f;
#pragma unroll
                for (int nt = 0; nt < 4; nt++) {
                    int col = k0 + nt * 16 + li;
                    float e = __expf((acc[mt][nt][rr] + bv) * ga[nt]);
                    sum += e;
                    Eb[((size_t)n * SS + s) * HW + col] = f2bf(e);
                }
                rp[mt][rr] = sum;
            }
        }
#pragma unroll
        for (int b = 1; b < 16; b <<= 1)
#pragma unroll
            for (int mt = 0; mt < 2; mt++)
#pragma unroll
                for (int rr = 0; rr < 4; rr++)
                    rp[mt][rr] += __shfl_xor(rp[mt][rr], b, 64);
        if (li == 0) {
#pragma unroll
            for (int mt = 0; mt < 2; mt++)
#pragma unroll
                for (int rr = 0; rr < 4; rr++)
                    atomicAdd(&rsum[n * SS + (w - 2) * 32 + mt * 16 + q * 4 + rr], rp[mt][rr]);
        }
    }
}

// ---------------- K2: MFMA graph: U = xs@E^T, P = E@E^T, split-K -> atomic accumulate -------
__global__ __launch_bounds__(256) void k_graph(const ushort* __restrict__ xsb,
                                               const ushort* __restrict__ Eb,
                                               float* __restrict__ U,
                                               float* __restrict__ P) {
    int n = blockIdx.y, sp = blockIdx.x;
    int kbase = sp * (HW / NSPLIT);
    int tid = threadIdx.x, lane = tid & 63, w = tid >> 6;
    int q = lane >> 4, li = lane & 15;
    bool isP = w >= 2;
    int half = w & 1;
    const ushort* Arow = isP ? Eb : xsb;
    f32x4 acc[2][4] = {};
    for (int ks = 0; ks < (HW / NSPLIT) / 32; ks++) {
        int kb = kbase + ks * 32 + q * 8;
        short8 af[2], bfr[4];
#pragma unroll
        for (int mt = 0; mt < 2; mt++) {
            int s = half * 32 + mt * 16 + li;
            uint4 t = *(const uint4*)&Arow[((size_t)n * SS + s) * HW + kb];
            af[mt] = *(short8*)&t;
        }
#pragma unroll
        for (int nt = 0; nt < 4; nt++) {
            int tt = nt * 16 + li;
            uint4 t = *(const uint4*)&Eb[((size_t)n * SS + tt) * HW + kb];
            bfr[nt] = *(short8*)&t;
        }
#pragma unroll
        for (int mt = 0; mt < 2; mt++)
#pragma unroll
            for (int nt = 0; nt < 4; nt++)
                acc[mt][nt] = __builtin_amdgcn_mfma_f32_16x16x32_bf16(af[mt], bfr[nt], acc[mt][nt], 0, 0, 0);
    }
    float* dst = (isP ? P : U) + (size_t)n * 4096;
#pragma unroll
    for (int mt = 0; mt < 2; mt++)
#pragma unroll
        for (int nt = 0; nt < 4; nt++)
#pragma unroll
            for (int rr = 0; rr < 4; rr++) {
                int row = half * 32 + mt * 16 + q * 4 + rr;
                int col = nt * 16 + li;
                atomicAdd(&dst[row * 64 + col], acc[mt][nt][rr]);
            }
}

// ---------------- K3: GCN + fold We: M' fp32 [c][t] AND bf16 fragment-ready Mf --------------
__global__ __launch_bounds__(256) void k_gcn(const float* __restrict__ U,
                                             const float* __restrict__ rsum,
                                             const float* __restrict__ W1,
                                             const float* __restrict__ W2,
                                             const float* __restrict__ We,
                                             float* __restrict__ M,
                                             ushort* __restrict__ Mf) {
    __shared__ __align__(16) float A[64 * 68];
    __shared__ __align__(16) float B[64 * 68];
    __shared__ __align__(16) float Cb[64 * 68];
    __shared__ float rs[64];
    int n = blockIdx.x;
    int cc = blockIdx.y;
    int tid = threadIdx.x;
    int t0 = tid >> 4, t1 = tid & 15;
    if (tid < 64) rs[tid] = 1.0f / rsum[n * SS + tid];
    __syncthreads();
#pragma unroll
    for (int i = 0; i < 16; i++) {
        int idx = tid + i * 256;
        int r = idx >> 6, cth = idx & 63;
        A[cth * 68 + r] = U[n * 4096 + idx] * rs[cth];
        B[cth * 68 + r] = W1[idx];
    }
    __syncthreads();
    {
        float acc[4][4] = {};
        for (int j = 0; j < 64; j++) {
            float4 a4 = *(const float4*)&A[j * 68 + t0 * 4];
            float4 b4 = *(const float4*)&B[j * 68 + t1 * 4];
            float a[4] = {a4.x, a4.y, a4.z, a4.w};
            float b[4] = {b4.x, b4.y, b4.z, b4.w};
#pragma unroll
            for (int p = 0; p < 4; p++)
#pragma unroll
                for (int qq = 0; qq < 4; qq++) acc[p][qq] += a[p] * b[qq];
        }
#pragma unroll
        for (int p = 0; p < 4; p++)
#pragma unroll
            for (int qq = 0; qq < 4; qq++) {
                acc[p][qq] -= A[(t1 * 4 + qq) * 68 + (t0 * 4 + p)];
                Cb[(t0 * 4 + p) * 68 + t1 * 4 + qq] = acc[p][qq];
            }
    }
    __syncthreads();
#pragma unroll
    for (int i = 0; i < 16; i++) {
        int idx = tid + i * 256;
        int r = idx >> 6, cth = idx & 63;
        B[cth * 68 + r] = W2[idx];
    }
    __syncthreads();
    {
        float acc[4][4] = {};
        for (int j = 0; j < 64; j++) {
            float4 a4 = *(const float4*)&B[j * 68 + t0 * 4];
            float4 b4 = *(const float4*)&Cb[j * 68 + t1 * 4];
            float a[4] = {a4.x, a4.y, a4.z, a4.w};
            float b[4] = {b4.x, b4.y, b4.z, b4.w};
#pragma unroll
            for (int p = 0; p < 4; p++)
#pragma unroll
                for (int qq = 0; qq < 4; qq++) acc[p][qq] += a[p] * b[qq];
        }
        __syncthreads();
#pragma unroll
        for (int p = 0; p < 4; p++)
#pragma unroll
            for (int qq = 0; qq < 4; qq++)
                A[(t0 * 4 + p) * 68 + t1 * 4 + qq] = fmaxf(acc[p][qq], 0.f);
    }
    __syncthreads();
#pragma unroll
    for (int i = 0; i < 16; i++) {
        int idx = tid + i * 256;
        int c = idx >> 6, j = idx & 63;
        B[j * 68 + c] = We[(cc * 64 + c) * 64 + j];
    }
    __syncthreads();
    {
        float acc[4][4] = {};
        for (int j = 0; j < 64; j++) {
            float4 a4 = *(const float4*)&B[j * 68 + t0 * 4];
            float4 b4 = *(const float4*)&A[j * 68 + t1 * 4];
            float a[4] = {a4.x, a4.y, a4.z, a4.w};
            float b[4] = {b4.x, b4.y, b4.z, b4.w};
#pragma unroll
            for (int p = 0; p < 4; p++)
#pragma unroll
                for (int qq = 0; qq < 4; qq++) acc[p][qq] += a[p] * b[qq];
        }
#pragma unroll
        for (int p = 0; p < 4; p++) {
            int c = cc * 64 + t0 * 4 + p;
            float v[4];
#pragma unroll
            for (int qq = 0; qq < 4; qq++) v[qq] = acc[p][qq] * rs[t1 * 4 + qq];
            float4 st = {v[0], v[1], v[2], v[3]};
            *(float4*)&M[((size_t)n * CC + c) * 64 + t1 * 4] = st;
#pragma unroll
            for (int qq = 0; qq < 4; qq++) {
                int t = t1 * 4 + qq;
                Mf[(size_t)n * 16384 + ((t >> 3) * 256 + c) * 8 + (t & 7)] = f2bf(v[qq]);
            }
        }
    }
}

// ---------------- K4: BN stats -> scale/bias (all-n LDS preload, 2-barrier body) ----------------
__global__ __launch_bounds__(256) void k_stats(const float* __restrict__ M,
                                               const float* __restrict__ P,
                                               const float* __restrict__ rsum,
                                               const float* __restrict__ gamma,
                                               const float* __restrict__ beta,
                                               float* __restrict__ sc,
                                               float* __restrict__ bi) {
    __shared__ float ms[NB][64];     // 4 KB: M rows for this channel, all n
    __shared__ float red[256];
    int c = blockIdx.x;
    int tid = threadIdx.x;
    for (int i = tid; i < NB * 64; i += 256) {
        int n = i >> 6, s = i & 63;
        ms[n][s] = M[((size_t)n * CC + c) * 64 + s];
    }
    __syncthreads();
    float qa = 0.f;
    for (int n = 0; n < NB; n++) {
        const float* Pn = P + n * 4096;
#pragma unroll
        for (int p = 0; p < 16; p++) {
            int e = p * 256 + tid;
            qa += ms[n][e >> 6] * ms[n][e & 63] * Pn[e];
        }
    }
    float sa = 0.f;
    for (int i = tid; i < NB * 64; i += 256) {
        int n = i >> 6, s = i & 63;
        sa += ms[n][s] * rsum[n * SS + s];
    }
    red[tid] = qa;
    __syncthreads();
    for (int off = 128; off > 0; off >>= 1) {
        if (tid < off) red[tid] += red[tid + off];
        __syncthreads();
    }
    float qtot = red[0];
    __syncthreads();
    red[tid] = sa;
    __syncthreads();
    for (int off = 128; off > 0; off >>= 1) {
        if (tid < off) red[tid] += red[tid + off];
        __syncthreads();
    }
    if (tid == 0) {
        float stot = red[0];
        const float invM = 1.0f / ((float)NB * (float)HW);
        float mean = stot * invM;
        float var = qtot * invM - mean * mean;
        float s = gamma[c] * rsqrtf(var + EPS);
        sc[c] = s;
        bi[c] = beta[c] - s * mean;
    }
}

// ---------------- K5: MFMA out v3: 128c x 128k tile, float4 I/O, STATIC acc indexing --------
// grid (72, NB): bx = kt*2 + ct. Epilogue mtc loop FULLY UNROLLED (rule #20: runtime-indexed
// ext_vector array spills whole acc to scratch -> was 241 MB WRITE_SIZE in v2).
__global__ __launch_bounds__(256) void k_out(const float* __restrict__ x,
                                             const ushort* __restrict__ Mf,
                                             const ushort* __restrict__ Eb,
                                             const float* __restrict__ sc,
                                             const float* __restrict__ bi,
                                             float* __restrict__ out) {
    __shared__ __align__(16) char shb[64 * 132 * 4];   // 33792 B
    ushort* Bl = (ushort*)shb;     // staging frag [kq 0..7][col 0..127][8] = 16 KB
    float* E2 = (float*)shb;       // epilogue chunk [64][132]
    int n = blockIdx.y;
    int kt = blockIdx.x >> 1, ct = blockIdx.x & 1;
    int k0 = kt * 128, c0 = ct * 128;
    int tid = threadIdx.x, lane = tid & 63, w = tid >> 6;
    int q = lane >> 4, li = lane & 15;
    {
        int nl = tid & 127, pr = tid >> 7;
#pragma unroll
        for (int kk = 0; kk < 4; kk++) {
            int kq = pr * 4 + kk;
            union { ushort u[8]; uint4 v; } tmp;
#pragma unroll
            for (int j = 0; j < 8; j++)
                tmp.u[j] = Eb[((size_t)n * SS + kq * 8 + j) * HW + k0 + nl];
            *(uint4*)&Bl[(kq * 128 + nl) * 8] = tmp.v;
        }
    }
    __syncthreads();
    f32x4 acc[2][8] = {};
#pragma unroll
    for (int ks = 0; ks < 2; ks++) {
        short8 af[2], bfr[8];
#pragma unroll
        for (int mt = 0; mt < 2; mt++) {
            int c = c0 + w * 32 + mt * 16 + li;
            uint4 t = *(const uint4*)&Mf[(size_t)n * 16384 + ((ks * 4 + q) * 256 + c) * 8];
            af[mt] = *(short8*)&t;
        }
#pragma unroll
        for (int nt = 0; nt < 8; nt++) {
            int nl = nt * 16 + li;
            uint4 t = *(const uint4*)&Bl[((ks * 4 + q) * 128 + nl) * 8];
            bfr[nt] = *(short8*)&t;
        }
#pragma unroll
        for (int mt = 0; mt < 2; mt++)
#pragma unroll
            for (int nt = 0; nt < 8; nt++)
                acc[mt][nt] = __builtin_amdgcn_mfma_f32_16x16x32_bf16(af[mt], bfr[nt], acc[mt][nt], 0, 0, 0);
    }
#pragma unroll
    for (int mtc = 0; mtc < 2; mtc++) {     // FULL unroll: acc[mtc] indices compile-time
        __syncthreads();     // protect E2 (aliases Bl on first pass / prev chunk after)
#pragma unroll
        for (int nt = 0; nt < 8; nt++)
#pragma unroll
            for (int rr = 0; rr < 4; rr++)
                E2[(w * 16 + q * 4 + rr) * 132 + nt * 16 + li] = acc[mtc][nt][rr];
        __syncthreads();
#pragma unroll
        for (int i = 0; i < 8; i++) {
            int r = (tid >> 5) + i * 8;            // 0..63
            int c4 = tid & 31;
            int c = c0 + (r >> 4) * 32 + mtc * 16 + (r & 15);
            float s_ = sc[c], bv = bi[c];
            float4 av = *(const float4*)&E2[r * 132 + c4 * 4];
            size_t base = ((size_t)n * CC + c) * HW + k0 + c4 * 4;
            float4 xv = *(const float4*)&x[base];
            float4 o;
            o.x = xv.x + s_ * av.x + bv;
            o.y = xv.y + s_ * av.y + bv;
            o.z = xv.z + s_ * av.z + bv;
            o.w = xv.w + s_ * av.w + bv;
            *(float4*)&out[base] = o;
        }
    }
}

extern "C" void kernel_launch(void* const* d_in, const int* in_sizes, int n_in,
                              void* d_out, int out_size, void* d_ws, size_t ws_size,
                              hipStream_t stream) {
    const float* x = (const float*)d_in[0];
    const float* edge = (const float*)d_in[1];
    const float* Ws = (const float*)d_in[2];
    const float* bs = (const float*)d_in[3];
    const float* Wp = (const float*)d_in[4];
    const float* bp = (const float*)d_in[5];
    const float* W1 = (const float*)d_in[6];
    const float* W2 = (const float*)d_in[7];
    const float* We = (const float*)d_in[8];
    const float* gamma = (const float*)d_in[9];
    const float* beta = (const float*)d_in[10];
    float* out = (float*)d_out;

    char* base = (char*)d_ws;
    ushort* Wf  = (ushort*)base;                    base += 65536;           // 64 KB
    ushort* xsb = (ushort*)base;                    base += 9437184;         // 9 MB
    ushort* Eb  = (ushort*)base;                    base += 9437184;
    float*  rsum= (float*)base;                     base += 4096;            // zeroed region start
    float*  U   = (float*)base;                     base += 262144;
    float*  P   = (float*)base;                     base += 262144;
    float*  M   = (float*)base;                     base += 1048576;
    ushort* Mf  = (ushort*)base;                    base += 524288;
    float*  sc  = (float*)base;                     base += 1024;
    float*  bi  = (float*)base;                     base += 1024;

    // zero rsum + U + P in one contiguous memset (4 KB + 256 KB + 256 KB)
    hipMemsetAsync(rsum, 0, 4096 + 262144 + 262144, stream);
    k_wf<<<128, 256, 0, stream>>>(Ws, Wp, Wf);
    k_proj<<<dim3(72, NB), 256, 0, stream>>>(x, Wf, bs, bp, edge, xsb, Eb, rsum);
    k_graph<<<dim3(NSPLIT, NB), 256, 0, stream>>>(xsb, Eb, U, P);
    k_gcn<<<dim3(NB, 4), 256, 0, stream>>>(U, rsum, W1, W2, We, M, Mf);
    k_stats<<<256, 256, 0, stream>>>(M, P, rsum, gamma, beta, sc, bi);
    k_out<<<dim3(72, NB), 256, 0, stream>>>(x, Mf, Eb, sc, bi, out);
}